// Round 11
// baseline (245.860 us; speedup 1.0000x reference)
//
#include <hip/hip_runtime.h>
#include <stdint.h>
#include <math.h>

#define A_ 9
#define N_ANCH 90000
#define PRE_NMS 6000
#define POST_NMS 300
#define NMS_TH 0.7f
#define NBINS 4096
#define CAND_CAP 8192
#define MASK_W 94        /* ceil(6000/64) */
#define NTILE 4465       /* 94*95/2 upper-triangle tiles */

/* ---- workspace byte offsets ---- */
#define OFF_HIST    0u         /* 4096*4 (zeroed by k_zero) */
#define OFF_BINCNT  16384u     /* 4096*4 (zeroed by k_zero) */
#define OFF_COLDONE 32768u     /* 96*4   (zeroed by k_zero) */
#define OFF_CAND    49408u     /* 8192*8 */
#define OFF_ORDER   114944u    /* 6000*4 */
#define OFF_TSCORE  138944u    /* 6000*4 */
#define OFF_TBOX    162944u    /* 6000*16 */
#define OFF_MASK    258944u    /* 6000*94*8 */

typedef unsigned long long u64;
typedef unsigned int u32;

__device__ __forceinline__ int score_bin(float s) {
    int bin = (int)(s * (float)NBINS);
    return bin < 0 ? 0 : (bin > NBINS - 1 ? NBINS - 1 : bin);
}

/* 0) zero hist + binCnt + col_done */
__global__ void __launch_bounds__(256) k_zero(char* __restrict__ ws) {
    int4* z4 = (int4*)(ws + OFF_HIST);
#pragma unroll
    for (int k = 0; k < 8; ++k)
        z4[k * 256 + threadIdx.x] = make_int4(0, 0, 0, 0);
    int* cd = (int*)(ws + OFF_COLDONE);
    if (threadIdx.x < 96) cd[threadIdx.x] = 0;
}

/* 1) global score histogram */
__global__ void k_hist(const float* __restrict__ cls, int* __restrict__ hist) {
    int n = blockIdx.x * blockDim.x + threadIdx.x;
    if (n >= N_ANCH) return;
    float s = cls[(n / A_) * (2 * A_) + A_ + (n % A_)];
    atomicAdd(&hist[score_bin(s)], 1);
}

/* per-block scan preamble: fills sufs[] (LDS), returns threshold T */
__device__ __forceinline__ int block_scan(const int* __restrict__ hist,
                                          int* sufs, int* sfx, int* tsh,
                                          int hl[16]) {
    int t = threadIdx.x;
    int csum = 0;
#pragma unroll
    for (int k = 0; k < 16; ++k) { hl[k] = hist[t * 16 + k]; csum += hl[k]; }
    sfx[t] = csum;
    if (t == 0) *tsh = 0;
    __syncthreads();
    for (int off = 1; off < 256; off <<= 1) {
        int v = (t + off < 256) ? sfx[t + off] : 0;
        __syncthreads();
        sfx[t] += v;
        __syncthreads();
    }
    int acc = sfx[t] - csum;
    int best = -1;
#pragma unroll
    for (int k = 15; k >= 0; --k) {
        sufs[t * 16 + k] = acc;
        acc += hl[k];
        if (best < 0 && acc >= PRE_NMS) best = t * 16 + k;
    }
    if (best >= 0) atomicMax(tsh, best);
    __syncthreads();
    return *tsh;
}

/* 2) per-block scan + compact into bin-segmented cand */
__global__ void __launch_bounds__(256) k_compact(const float* __restrict__ cls,
                                                 const int* __restrict__ hist,
                                                 int* __restrict__ binCnt,
                                                 u64* __restrict__ cand) {
    __shared__ int sufs[NBINS];
    __shared__ int sfx[256];
    __shared__ int tsh;
    int hl[16];
    int T = block_scan(hist, sufs, sfx, &tsh, hl);
    int n = blockIdx.x * 256 + threadIdx.x;
    if (n >= N_ANCH) return;
    float s = cls[(n / A_) * (2 * A_) + A_ + (n % A_)];
    int bin = score_bin(s);
    if (bin >= T) {
        int slot = atomicAdd(&binCnt[bin], 1);
        int p = sufs[bin] + slot;
        if (p < CAND_CAP) {
            u64 key = ((u64)__float_as_uint(s) << 32) | (u64)(0xFFFFFFFFu - (u32)n);
            cand[p] = key;
        }
    }
}

/* 3) per-block scan + exact rank + box decode/clip at rank */
__global__ void __launch_bounds__(256) k_rank(const u64* __restrict__ cand,
                                              const int* __restrict__ hist,
                                              const float* __restrict__ anchors,
                                              const float* __restrict__ bbox,
                                              const float* __restrict__ im_info,
                                              int* __restrict__ order,
                                              float* __restrict__ tscore,
                                              float* __restrict__ tb) {
#pragma clang fp contract(off)
    __shared__ int sufs[NBINS];
    __shared__ int sfx[256];
    __shared__ int tsh;
    int hl[16];
    int T = block_scan(hist, sufs, sfx, &tsh, hl);
    int M = sufs[T] + hist[T];
    if (M > CAND_CAP) M = CAND_CAP;
    int i = blockIdx.x * 256 + threadIdx.x;
    if (i >= M) return;
    u64 ki = cand[i];
    float sc = __uint_as_float((u32)(ki >> 32));
    int bin = score_bin(sc);
    int base = sufs[bin];
    int end = base + hist[bin];
    if (end > CAND_CAP) end = CAND_CAP;
    int rank = base;
    for (int j = base; j < end; ++j)
        rank += (cand[j] > ki) ? 1 : 0;
    if (rank >= PRE_NMS) return;

    int n = (int)(0xFFFFFFFFu - (u32)(ki & 0xFFFFFFFFull));
    order[rank] = n;
    tscore[rank] = sc;

    int hw = n / A_, a = n % A_;
    const float* an = anchors + (size_t)n * 4;
    const float* d  = bbox + (size_t)hw * (4 * A_) + a * 4;
    float w  = an[2] - an[0] + 1.0f;
    float h  = an[3] - an[1] + 1.0f;
    float cx = an[0] + 0.5f * w;
    float cy = an[1] + 0.5f * h;
    float pcx = d[0] * w + cx;
    float pcy = d[1] * h + cy;
    float pw  = expf(d[2]) * w;
    float ph  = expf(d[3]) * h;
    float x1 = pcx - 0.5f * pw;
    float y1 = pcy - 0.5f * ph;
    float x2 = pcx + 0.5f * pw;
    float y2 = pcy + 0.5f * ph;
    float im_h = im_info[0], im_w = im_info[1];
    x1 = fminf(fmaxf(x1, 0.0f), im_w - 1.0f);
    y1 = fminf(fmaxf(y1, 0.0f), im_h - 1.0f);
    x2 = fminf(fmaxf(x2, 0.0f), im_w - 1.0f);
    y2 = fminf(fmaxf(y2, 0.0f), im_h - 1.0f);
    tb[rank * 4 + 0] = x1;
    tb[rank * 4 + 1] = y1;
    tb[rank * 4 + 2] = x2;
    tb[rank * 4 + 3] = y2;
}

/* 4) FUSED mask + reduce + output.
      blockIdx 0 = consumer (scalar-chain greedy reduce + output gather),
      blockIdx 1..NTILE = producers (one upper-tri 64x64 IoU tile each,
      column-major triangular order; release-add col_done[cb] when done).
      Consumer acquire-spins on col_done[nc]==nc+1 before touching column nc. */
__global__ void __launch_bounds__(64)
k_mask_reduce(const float* __restrict__ tb, u64* __restrict__ mask,
              int* __restrict__ col_done,
              const int* __restrict__ order, const float* __restrict__ tscore,
              const float* __restrict__ trans, float* __restrict__ out) {
#pragma clang fp contract(off)
    if (blockIdx.x != 0) {
        /* ---- producer: tile t5, column-major triangular decode ---- */
        int t5 = (int)blockIdx.x - 1;
        int cb = (int)((sqrtf(8.0f * (float)t5 + 1.0f) - 1.0f) * 0.5f);
        while ((cb + 1) * (cb + 2) / 2 <= t5) ++cb;
        while (cb > 0 && cb * (cb + 1) / 2 > t5) --cb;
        int rb = t5 - cb * (cb + 1) / 2;        /* rb in [0, cb] */

        __shared__ float cbx[64][4];
        __shared__ float car[64];
        int t = threadIdx.x;
        int j0 = cb * 64;
        int jj = j0 + t;
        if (jj < PRE_NMS) {
            float bx1 = tb[jj * 4 + 0], by1 = tb[jj * 4 + 1];
            float bx2 = tb[jj * 4 + 2], by2 = tb[jj * 4 + 3];
            cbx[t][0] = bx1; cbx[t][1] = by1; cbx[t][2] = bx2; cbx[t][3] = by2;
            car[t] = (bx2 - bx1 + 1.0f) * (by2 - by1 + 1.0f);
        } else {
            cbx[t][0] = 0; cbx[t][1] = 0; cbx[t][2] = -2; cbx[t][3] = -2;
            car[t] = 1.0f;
        }
        __syncthreads();
        int row = rb * 64 + t;
        if (row < PRE_NMS) {
            float x1 = tb[row * 4 + 0], y1 = tb[row * 4 + 1];
            float x2 = tb[row * 4 + 2], y2 = tb[row * 4 + 3];
            float ai = (x2 - x1 + 1.0f) * (y2 - y1 + 1.0f);
            u64 bits = 0;
            for (int c = 0; c < 64; ++c) {
                int j = j0 + c;
                if (j > row && j < PRE_NMS) {
                    float xx1 = fmaxf(x1, cbx[c][0]);
                    float yy1 = fmaxf(y1, cbx[c][1]);
                    float xx2 = fminf(x2, cbx[c][2]);
                    float yy2 = fminf(y2, cbx[c][3]);
                    float iw = fmaxf(xx2 - xx1 + 1.0f, 0.0f);
                    float ih = fmaxf(yy2 - yy1 + 1.0f, 0.0f);
                    float inter = iw * ih;
                    float iou = inter / (ai + car[c] - inter);
                    if (iou > NMS_TH) bits |= (1ull << c);
                }
            }
            mask[(size_t)row * MASK_W + cb] = bits;
        }
        __syncthreads();                        /* all lanes' stores issued+waited */
        if (t == 0) {
            __threadfence();                    /* device-scope release of mask tile */
            __hip_atomic_fetch_add(&col_done[cb], 1, __ATOMIC_RELEASE,
                                   __HIP_MEMORY_SCOPE_AGENT);
        }
        return;
    }

    /* ---- consumer: greedy reduce (scalar chain) + output gather ---- */
    __shared__ int keep_s[POST_NMS];
    const int lane = threadIdx.x;
    while (__hip_atomic_load(&col_done[0], __ATOMIC_ACQUIRE,
                             __HIP_MEMORY_SCOPE_AGENT) < 1) {}
    u64 dwc = mask[(size_t)lane * MASK_W + 0];
    int cnt = 0;
    u64 cur = 0;
    for (int c = 0; c < MASK_W; ++c) {
        int nc = c + 1;
        u64 dwn = 0;
        if (nc < MASK_W) {
            while (__hip_atomic_load(&col_done[nc], __ATOMIC_ACQUIRE,
                                     __HIP_MEMORY_SCOPE_AGENT) < nc + 1) {}
            int rn = nc * 64 + lane;
            if (rn < PRE_NMS) dwn = mask[(size_t)rn * MASK_W + nc];
        }
        int nrows = PRE_NMS - c * 64; if (nrows > 64) nrows = 64;
        u64 vm = (nrows >= 64) ? ~0ull : ((1ull << nrows) - 1ull);
        u32 dlo_v = (u32)dwc, dhi_v = (u32)(dwc >> 32);
        int cnt0 = cnt;
        u64 keptw = 0;
        u64 freeb = (~cur) & vm;
        while (freeb != 0ull && cnt < POST_NMS) {
            u32 bs;
            asm("s_ff1_i32_b64 %0, %1" : "=s"(bs) : "s"(freeb));
            u32 dlo, dhi;
            asm("v_readlane_b32 %0, %1, %2" : "=s"(dlo) : "v"(dlo_v), "s"(bs));
            asm("v_readlane_b32 %0, %1, %2" : "=s"(dhi) : "v"(dhi_v), "s"(bs));
            u64 bit = 1ull << bs;
            keptw |= bit;
            cur |= (((u64)dhi << 32) | (u64)dlo) | bit;
            cnt++;
            freeb = (~cur) & vm;
        }
        if ((keptw >> lane) & 1ull) {
            int pos = cnt0 + __popcll(keptw & ((1ull << lane) - 1ull));
            keep_s[pos] = c * 64 + lane;
        }
        if (cnt >= POST_NMS || nc >= MASK_W) break;
        u64 acc = 0;
#pragma unroll
        for (int s = 0; s < 5; ++s) {
            int p = s * 64 + lane;
            if (p < cnt) {
                int kr = keep_s[p];
                acc |= mask[(size_t)kr * MASK_W + nc];
            }
        }
#pragma unroll
        for (int m = 32; m >= 1; m >>= 1)
            acc |= (u64)__shfl_xor((unsigned long long)acc, m, 64);
        u32 clo = __builtin_amdgcn_readfirstlane((u32)acc);
        u32 chi = __builtin_amdgcn_readfirstlane((u32)(acc >> 32));
        cur = ((u64)chi << 32) | (u64)clo;
        dwc = dwn;
    }
    for (int r = cnt + lane; r < POST_NMS; r += 64) keep_s[r] = 0;
    __syncthreads();
    for (int row = lane; row < POST_NMS; row += 64) {
        int r = keep_s[row];
        int n = order[r];
        out[row * 5 + 0] = 0.0f;
        out[row * 5 + 1] = tb[r * 4 + 0];
        out[row * 5 + 2] = tb[r * 4 + 1];
        out[row * 5 + 3] = tb[r * 4 + 2];
        out[row * 5 + 4] = tb[r * 4 + 3];
        out[POST_NMS * 5 + row] = tscore[r];
        int hw = n / A_, a = n % A_;
        const float* tp = trans + (size_t)hw * (6 * A_) + a * 6;
#pragma unroll
        for (int c2 = 0; c2 < 6; ++c2)
            out[POST_NMS * 6 + row * 6 + c2] = tp[c2];
    }
}

extern "C" void kernel_launch(void* const* d_in, const int* in_sizes, int n_in,
                              void* d_out, int out_size, void* d_ws, size_t ws_size,
                              hipStream_t stream) {
    const float* anchors = (const float*)d_in[0];
    const float* cls     = (const float*)d_in[1];
    const float* bbox    = (const float*)d_in[2];
    const float* trans   = (const float*)d_in[3];
    const float* im_info = (const float*)d_in[4];
    float* out = (float*)d_out;
    char* ws = (char*)d_ws;

    int*   hist    = (int*)(ws + OFF_HIST);
    int*   binCnt  = (int*)(ws + OFF_BINCNT);
    int*   coldone = (int*)(ws + OFF_COLDONE);
    u64*   cand    = (u64*)(ws + OFF_CAND);
    int*   order   = (int*)(ws + OFF_ORDER);
    float* tscore  = (float*)(ws + OFF_TSCORE);
    float* tb      = (float*)(ws + OFF_TBOX);
    u64*   mask    = (u64*)(ws + OFF_MASK);

    int nb = (N_ANCH + 255) / 256;
    k_zero<<<1, 256, 0, stream>>>(ws);
    k_hist<<<nb, 256, 0, stream>>>(cls, hist);
    k_compact<<<nb, 256, 0, stream>>>(cls, hist, binCnt, cand);
    k_rank<<<CAND_CAP / 256, 256, 0, stream>>>(cand, hist, anchors, bbox, im_info,
                                               order, tscore, tb);
    k_mask_reduce<<<NTILE + 1, 64, 0, stream>>>(tb, mask, coldone,
                                                order, tscore, trans, out);
}

// Round 12
// 83.231 us; speedup vs baseline: 2.9540x; 2.9540x over previous
//
#include <hip/hip_runtime.h>
#include <stdint.h>
#include <math.h>

#define A_ 9
#define N_ANCH 90000
#define PRE_NMS 6000
#define POST_NMS 300
#define NMS_TH 0.7f
#define NBINS 4096
#define CAND_CAP 8192
#define MASK_W 94        /* ceil(6000/64) */
#define NPAIR 47         /* MASK_W/2 column pairs */
#define NTILE 4465       /* 94*95/2 upper-triangle tiles */

/* ---- workspace byte offsets ---- */
#define OFF_HIST    0u         /* 4096*4 (zeroed by k_zero) */
#define OFF_BINCNT  16384u     /* 4096*4 (zeroed by k_zero) */
#define OFF_CAND    49408u     /* 8192*8 */
#define OFF_ORDER   114944u    /* 6000*4 */
#define OFF_TSCORE  138944u    /* 6000*4 */
#define OFF_TBOX    162944u    /* 6000*16 */
#define OFF_MASK    258944u    /* 6000*94*8 */

typedef unsigned long long u64;
typedef unsigned int u32;

__device__ __forceinline__ int score_bin(float s) {
    int bin = (int)(s * (float)NBINS);
    return bin < 0 ? 0 : (bin > NBINS - 1 ? NBINS - 1 : bin);
}

/* 0) zero hist + binCnt (32 KB, 8 blocks) */
__global__ void __launch_bounds__(256) k_zero(int4* __restrict__ z4) {
    z4[blockIdx.x * 256 + threadIdx.x] = make_int4(0, 0, 0, 0);
}

/* 1) global score histogram */
__global__ void k_hist(const float* __restrict__ cls, int* __restrict__ hist) {
    int n = blockIdx.x * blockDim.x + threadIdx.x;
    if (n >= N_ANCH) return;
    float s = cls[(n / A_) * (2 * A_) + A_ + (n % A_)];
    atomicAdd(&hist[score_bin(s)], 1);
}

/* per-block scan preamble: fills sufs[] (LDS), returns threshold T */
__device__ __forceinline__ int block_scan(const int* __restrict__ hist,
                                          int* sufs, int* sfx, int* tsh,
                                          int hl[16]) {
    int t = threadIdx.x;
    int csum = 0;
#pragma unroll
    for (int k = 0; k < 16; ++k) { hl[k] = hist[t * 16 + k]; csum += hl[k]; }
    sfx[t] = csum;
    if (t == 0) *tsh = 0;
    __syncthreads();
    for (int off = 1; off < 256; off <<= 1) {
        int v = (t + off < 256) ? sfx[t + off] : 0;
        __syncthreads();
        sfx[t] += v;
        __syncthreads();
    }
    int acc = sfx[t] - csum;
    int best = -1;
#pragma unroll
    for (int k = 15; k >= 0; --k) {
        sufs[t * 16 + k] = acc;
        acc += hl[k];
        if (best < 0 && acc >= PRE_NMS) best = t * 16 + k;
    }
    if (best >= 0) atomicMax(tsh, best);
    __syncthreads();
    return *tsh;
}

/* 2) per-block scan + compact into bin-segmented cand */
__global__ void __launch_bounds__(256) k_compact(const float* __restrict__ cls,
                                                 const int* __restrict__ hist,
                                                 int* __restrict__ binCnt,
                                                 u64* __restrict__ cand) {
    __shared__ int sufs[NBINS];
    __shared__ int sfx[256];
    __shared__ int tsh;
    int hl[16];
    int T = block_scan(hist, sufs, sfx, &tsh, hl);
    int n = blockIdx.x * 256 + threadIdx.x;
    if (n >= N_ANCH) return;
    float s = cls[(n / A_) * (2 * A_) + A_ + (n % A_)];
    int bin = score_bin(s);
    if (bin >= T) {
        int slot = atomicAdd(&binCnt[bin], 1);
        int p = sufs[bin] + slot;
        if (p < CAND_CAP) {
            u64 key = ((u64)__float_as_uint(s) << 32) | (u64)(0xFFFFFFFFu - (u32)n);
            cand[p] = key;
        }
    }
}

/* 3) per-block scan + exact rank + box decode/clip at rank */
__global__ void __launch_bounds__(256) k_rank(const u64* __restrict__ cand,
                                              const int* __restrict__ hist,
                                              const float* __restrict__ anchors,
                                              const float* __restrict__ bbox,
                                              const float* __restrict__ im_info,
                                              int* __restrict__ order,
                                              float* __restrict__ tscore,
                                              float* __restrict__ tb) {
#pragma clang fp contract(off)
    __shared__ int sufs[NBINS];
    __shared__ int sfx[256];
    __shared__ int tsh;
    int hl[16];
    int T = block_scan(hist, sufs, sfx, &tsh, hl);
    int M = sufs[T] + hist[T];
    if (M > CAND_CAP) M = CAND_CAP;
    int i = blockIdx.x * 256 + threadIdx.x;
    if (i >= M) return;
    u64 ki = cand[i];
    float sc = __uint_as_float((u32)(ki >> 32));
    int bin = score_bin(sc);
    int base = sufs[bin];
    int end = base + hist[bin];
    if (end > CAND_CAP) end = CAND_CAP;
    int rank = base;
    for (int j = base; j < end; ++j)
        rank += (cand[j] > ki) ? 1 : 0;
    if (rank >= PRE_NMS) return;

    int n = (int)(0xFFFFFFFFu - (u32)(ki & 0xFFFFFFFFull));
    order[rank] = n;
    tscore[rank] = sc;

    int hw = n / A_, a = n % A_;
    const float* an = anchors + (size_t)n * 4;
    const float* d  = bbox + (size_t)hw * (4 * A_) + a * 4;
    float w  = an[2] - an[0] + 1.0f;
    float h  = an[3] - an[1] + 1.0f;
    float cx = an[0] + 0.5f * w;
    float cy = an[1] + 0.5f * h;
    float pcx = d[0] * w + cx;
    float pcy = d[1] * h + cy;
    float pw  = expf(d[2]) * w;
    float ph  = expf(d[3]) * h;
    float x1 = pcx - 0.5f * pw;
    float y1 = pcy - 0.5f * ph;
    float x2 = pcx + 0.5f * pw;
    float y2 = pcy + 0.5f * ph;
    float im_h = im_info[0], im_w = im_info[1];
    x1 = fminf(fmaxf(x1, 0.0f), im_w - 1.0f);
    y1 = fminf(fmaxf(y1, 0.0f), im_h - 1.0f);
    x2 = fminf(fmaxf(x2, 0.0f), im_w - 1.0f);
    y2 = fminf(fmaxf(y2, 0.0f), im_h - 1.0f);
    tb[rank * 4 + 0] = x1;
    tb[rank * 4 + 1] = y1;
    tb[rank * 4 + 2] = x2;
    tb[rank * 4 + 3] = y2;
}

/* 4) suppression bitmask — one 64x64 upper-tri tile per WAVE (4 waves/block),
      per-wave LDS staging (lgkmcnt + wave_barrier, no __syncthreads),
      float4 box loads. */
__global__ void __launch_bounds__(256) k_mask(const float4* __restrict__ tb4,
                                              u64* __restrict__ mask) {
#pragma clang fp contract(off)
    __shared__ float sbox[4][64 * 5];
    int w = threadIdx.x >> 6, lane = threadIdx.x & 63;
    int t5 = (int)blockIdx.x * 4 + w;
    if (t5 >= NTILE) return;
    /* triangular decode: t5 = cb*(cb+1)/2 + rb, rb in [0,cb] */
    int cb = (int)((sqrtf(8.0f * (float)t5 + 1.0f) - 1.0f) * 0.5f);
    while ((cb + 1) * (cb + 2) / 2 <= t5) ++cb;
    while (cb > 0 && cb * (cb + 1) / 2 > t5) --cb;
    int rb = t5 - cb * (cb + 1) / 2;

    float* wr = sbox[w];
    int j0 = cb * 64;
    int jj = j0 + lane;
    float4 b;
    float ar;
    if (jj < PRE_NMS) {
        b = tb4[jj];
        ar = (b.z - b.x + 1.0f) * (b.w - b.y + 1.0f);
    } else {
        b = make_float4(0.0f, 0.0f, -2.0f, -2.0f);
        ar = 1.0f;
    }
    wr[lane * 5 + 0] = b.x; wr[lane * 5 + 1] = b.y;
    wr[lane * 5 + 2] = b.z; wr[lane * 5 + 3] = b.w;
    wr[lane * 5 + 4] = ar;
    asm volatile("s_waitcnt lgkmcnt(0)" ::: "memory");
    __builtin_amdgcn_wave_barrier();

    int row = rb * 64 + lane;
    if (row >= PRE_NMS) return;
    float4 r4 = tb4[row];
    float ai = (r4.z - r4.x + 1.0f) * (r4.w - r4.y + 1.0f);
    u64 bits = 0;
    for (int c = 0; c < 64; ++c) {
        int j = j0 + c;
        if (j > row && j < PRE_NMS) {
            float xx1 = fmaxf(r4.x, wr[c * 5 + 0]);
            float yy1 = fmaxf(r4.y, wr[c * 5 + 1]);
            float xx2 = fminf(r4.z, wr[c * 5 + 2]);
            float yy2 = fminf(r4.w, wr[c * 5 + 3]);
            float iw = fmaxf(xx2 - xx1 + 1.0f, 0.0f);
            float ih = fmaxf(yy2 - yy1 + 1.0f, 0.0f);
            float inter = iw * ih;
            float iou = inter / (ai + wr[c * 5 + 4] - inter);
            if (iou > NMS_TH) bits |= (1ull << c);
        }
    }
    mask[(size_t)row * MASK_W + cb] = bits;
}

/* 5) greedy reduce, scalar per-keep chain, 128-row (2-column) chunks:
      - prefetch per pair: dwc0 (diag col c0), dcx (col c1 word of c0-rows,
        contiguous 16B with dwc0), dwc1 (diag col c1).
      - keep in c0 ORs diag into cur0 AND cross word into cur1 (2 extra readlanes).
      - transition: gather BOTH next-pair words per kept row (16B contiguous),
        two butterflies interleaved. Transitions halved vs per-column. */
__global__ void __launch_bounds__(256) k_reduce_out(const u64* __restrict__ mask,
                                                    const int* __restrict__ order,
                                                    const float* __restrict__ tb,
                                                    const float* __restrict__ tscore,
                                                    const float* __restrict__ trans,
                                                    float* __restrict__ out) {
    __shared__ int keep_s[POST_NMS];
    if (threadIdx.x < 64) {
        const int lane = threadIdx.x;
        int cnt = 0;
        u64 cur0 = 0, cur1 = 0;               /* uniform (SGPR) pair words */
        /* prefetch pair 0 */
        u64 dwc0 = mask[(size_t)lane * MASK_W + 0];
        u64 dcx  = mask[(size_t)lane * MASK_W + 1];
        u64 dwc1 = mask[(size_t)(64 + lane) * MASK_W + 1];
        for (int p = 0; p < NPAIR; ++p) {
            int c0 = 2 * p, c1 = 2 * p + 1;
            /* prefetch next pair */
            u64 n0 = 0, nx = 0, n1 = 0;
            if (p + 1 < NPAIR) {
                int r0 = (c0 + 2) * 64 + lane;
                const u64* rp = mask + (size_t)r0 * MASK_W + (c0 + 2);
                n0 = rp[0];
                nx = rp[1];
                int r1 = (c0 + 3) * 64 + lane;
                if (r1 < PRE_NMS) n1 = mask[(size_t)r1 * MASK_W + (c0 + 3)];
            }
            /* ---- column c0 (always 64 valid rows) ---- */
            {
                u32 dlo_v = (u32)dwc0, dhi_v = (u32)(dwc0 >> 32);
                u32 xlo_v = (u32)dcx,  xhi_v = (u32)(dcx >> 32);
                int cnt0 = cnt;
                u64 keptw = 0;
                u64 freeb = ~cur0;
                while (freeb != 0ull && cnt < POST_NMS) {
                    u32 bs;
                    asm("s_ff1_i32_b64 %0, %1" : "=s"(bs) : "s"(freeb));
                    u32 dlo, dhi, xlo, xhi;
                    asm("v_readlane_b32 %0, %1, %2" : "=s"(dlo) : "v"(dlo_v), "s"(bs));
                    asm("v_readlane_b32 %0, %1, %2" : "=s"(dhi) : "v"(dhi_v), "s"(bs));
                    asm("v_readlane_b32 %0, %1, %2" : "=s"(xlo) : "v"(xlo_v), "s"(bs));
                    asm("v_readlane_b32 %0, %1, %2" : "=s"(xhi) : "v"(xhi_v), "s"(bs));
                    u64 bit = 1ull << bs;
                    keptw |= bit;
                    cur0 |= (((u64)dhi << 32) | (u64)dlo) | bit;
                    cur1 |= (((u64)xhi << 32) | (u64)xlo);
                    cnt++;
                    freeb = ~cur0;
                }
                if ((keptw >> lane) & 1ull) {
                    int pos = cnt0 + __popcll(keptw & ((1ull << lane) - 1ull));
                    keep_s[pos] = c0 * 64 + lane;
                }
            }
            if (cnt >= POST_NMS) break;
            /* ---- column c1 (48 valid rows in last pair) ---- */
            {
                int nrows = PRE_NMS - c1 * 64; if (nrows > 64) nrows = 64;
                u64 vm = (nrows >= 64) ? ~0ull : ((1ull << nrows) - 1ull);
                u32 dlo_v = (u32)dwc1, dhi_v = (u32)(dwc1 >> 32);
                int cnt0 = cnt;
                u64 keptw = 0;
                u64 freeb = (~cur1) & vm;
                while (freeb != 0ull && cnt < POST_NMS) {
                    u32 bs;
                    asm("s_ff1_i32_b64 %0, %1" : "=s"(bs) : "s"(freeb));
                    u32 dlo, dhi;
                    asm("v_readlane_b32 %0, %1, %2" : "=s"(dlo) : "v"(dlo_v), "s"(bs));
                    asm("v_readlane_b32 %0, %1, %2" : "=s"(dhi) : "v"(dhi_v), "s"(bs));
                    u64 bit = 1ull << bs;
                    keptw |= bit;
                    cur1 |= (((u64)dhi << 32) | (u64)dlo) | bit;
                    cnt++;
                    freeb = (~cur1) & vm;
                }
                if ((keptw >> lane) & 1ull) {
                    int pos = cnt0 + __popcll(keptw & ((1ull << lane) - 1ull));
                    keep_s[pos] = c1 * 64 + lane;
                }
            }
            if (cnt >= POST_NMS || p + 1 >= NPAIR) break;
            /* ---- transition: gather words c0+2, c0+3 of all kept rows ---- */
            u64 a0 = 0, a1 = 0;
#pragma unroll
            for (int s = 0; s < 5; ++s) {
                int pi = s * 64 + lane;
                if (pi < cnt) {
                    int kr = keep_s[pi];
                    const u64* rp = mask + (size_t)kr * MASK_W + (c0 + 2);
                    a0 |= rp[0];
                    a1 |= rp[1];
                }
            }
#pragma unroll
            for (int m = 32; m >= 1; m >>= 1) {
                a0 |= (u64)__shfl_xor((unsigned long long)a0, m, 64);
                a1 |= (u64)__shfl_xor((unsigned long long)a1, m, 64);
            }
            {
                u32 lo0 = __builtin_amdgcn_readfirstlane((u32)a0);
                u32 hi0 = __builtin_amdgcn_readfirstlane((u32)(a0 >> 32));
                u32 lo1 = __builtin_amdgcn_readfirstlane((u32)a1);
                u32 hi1 = __builtin_amdgcn_readfirstlane((u32)(a1 >> 32));
                cur0 = ((u64)hi0 << 32) | (u64)lo0;
                cur1 = ((u64)hi1 << 32) | (u64)lo1;
            }
            dwc0 = n0; dcx = nx; dwc1 = n1;
        }
        for (int r = cnt + lane; r < POST_NMS; r += 64) keep_s[r] = 0;
    }
    __syncthreads();
    for (int row = threadIdx.x; row < POST_NMS; row += 256) {
        int r = keep_s[row];
        int n = order[r];
        out[row * 5 + 0] = 0.0f;
        out[row * 5 + 1] = tb[r * 4 + 0];
        out[row * 5 + 2] = tb[r * 4 + 1];
        out[row * 5 + 3] = tb[r * 4 + 2];
        out[row * 5 + 4] = tb[r * 4 + 3];
        out[POST_NMS * 5 + row] = tscore[r];
        int hw = n / A_, a = n % A_;
        const float* tp = trans + (size_t)hw * (6 * A_) + a * 6;
#pragma unroll
        for (int c = 0; c < 6; ++c)
            out[POST_NMS * 6 + row * 6 + c] = tp[c];
    }
}

extern "C" void kernel_launch(void* const* d_in, const int* in_sizes, int n_in,
                              void* d_out, int out_size, void* d_ws, size_t ws_size,
                              hipStream_t stream) {
    const float* anchors = (const float*)d_in[0];
    const float* cls     = (const float*)d_in[1];
    const float* bbox    = (const float*)d_in[2];
    const float* trans   = (const float*)d_in[3];
    const float* im_info = (const float*)d_in[4];
    float* out = (float*)d_out;
    char* ws = (char*)d_ws;

    int*   hist   = (int*)(ws + OFF_HIST);
    int*   binCnt = (int*)(ws + OFF_BINCNT);
    u64*   cand   = (u64*)(ws + OFF_CAND);
    int*   order  = (int*)(ws + OFF_ORDER);
    float* tscore = (float*)(ws + OFF_TSCORE);
    float* tb     = (float*)(ws + OFF_TBOX);
    u64*   mask   = (u64*)(ws + OFF_MASK);

    int nb = (N_ANCH + 255) / 256;
    k_zero<<<8, 256, 0, stream>>>((int4*)hist);
    k_hist<<<nb, 256, 0, stream>>>(cls, hist);
    k_compact<<<nb, 256, 0, stream>>>(cls, hist, binCnt, cand);
    k_rank<<<CAND_CAP / 256, 256, 0, stream>>>(cand, hist, anchors, bbox, im_info,
                                               order, tscore, tb);
    k_mask<<<(NTILE + 3) / 4, 256, 0, stream>>>((const float4*)tb, mask);
    k_reduce_out<<<1, 256, 0, stream>>>(mask, order, tb, tscore, trans, out);
}